// Round 12
// baseline (91.827 us; speedup 1.0000x reference)
//
#include <hip/hip_runtime.h>

#define T_LEN 2048

typedef float f4 __attribute__((ext_vector_type(4)));

// --- one timestep ------------------------------------------------------------
// h_new[j] = relu( x_t*wih[j] + bias[j] + sum_k W_hh[j,k]*h[k] )
// Same 21 ops / 4 chains as R6 (best, 91.8us); ONLY the order differs:
// DPP runs split 7/4/4 by hoisting the two tail adds into the stream
// (adjacency-penalty discriminator: 14 -> 12 DPP-DPP adjacencies).
// Hazard: first DPP read of h is inst 3 after the previous max write.
__device__ __forceinline__ void step_r(float& h, float xs, const float (&w)[16],
                                       float wih, float bias) {
  float a0, a1, a2, a3;
  asm("v_fma_f32 %0, %5, %6, %7\n\t"                                          // 1: a0 = xs*wih+bias
      "v_fmac_f32 %0, %4, %8\n\t"                                             // 2: a0 += h*w0
      "v_fmac_f32_dpp %0, %4, %9  row_ror:1  row_mask:0xf bank_mask:0xf\n\t"  // 3:  a0 chain
      "v_fmac_f32_dpp %0, %4, %10 row_ror:2  row_mask:0xf bank_mask:0xf\n\t"  // 4
      "v_fmac_f32_dpp %0, %4, %11 row_ror:3  row_mask:0xf bank_mask:0xf\n\t"  // 5
      "v_mul_f32_dpp  %1, %4, %12 row_ror:4  row_mask:0xf bank_mask:0xf\n\t"  // 6:  a1 chain
      "v_fmac_f32_dpp %1, %4, %13 row_ror:5  row_mask:0xf bank_mask:0xf\n\t"  // 7
      "v_fmac_f32_dpp %1, %4, %14 row_ror:6  row_mask:0xf bank_mask:0xf\n\t"  // 8
      "v_fmac_f32_dpp %1, %4, %15 row_ror:7  row_mask:0xf bank_mask:0xf\n\t"  // 9
      "v_add_f32 %0, %0, %1\n\t"                                              // 10: BREAK a0 += a1
      "v_mul_f32_dpp  %2, %4, %16 row_ror:8  row_mask:0xf bank_mask:0xf\n\t"  // 11: a2 chain
      "v_fmac_f32_dpp %2, %4, %17 row_ror:9  row_mask:0xf bank_mask:0xf\n\t"  // 12
      "v_fmac_f32_dpp %2, %4, %18 row_ror:10 row_mask:0xf bank_mask:0xf\n\t"  // 13
      "v_fmac_f32_dpp %2, %4, %19 row_ror:11 row_mask:0xf bank_mask:0xf\n\t"  // 14
      "v_add_f32 %0, %0, %2\n\t"                                              // 15: BREAK a0 += a2
      "v_mul_f32_dpp  %3, %4, %20 row_ror:12 row_mask:0xf bank_mask:0xf\n\t"  // 16: a3 chain
      "v_fmac_f32_dpp %3, %4, %21 row_ror:13 row_mask:0xf bank_mask:0xf\n\t"  // 17
      "v_fmac_f32_dpp %3, %4, %22 row_ror:14 row_mask:0xf bank_mask:0xf\n\t"  // 18
      "v_fmac_f32_dpp %3, %4, %23 row_ror:15 row_mask:0xf bank_mask:0xf\n\t"  // 19
      "v_add_f32 %0, %0, %3\n\t"                                              // 20: a0 += a3
      "v_max_f32 %4, 0, %0"                                                   // 21: relu -> h
      : "=&v"(a0), "=&v"(a1), "=&v"(a2), "=&v"(a3), "+v"(h)
      : "v"(xs), "v"(wih), "v"(bias),
        "v"(w[0]), "v"(w[1]), "v"(w[2]), "v"(w[3]),
        "v"(w[4]), "v"(w[5]), "v"(w[6]), "v"(w[7]),
        "v"(w[8]), "v"(w[9]), "v"(w[10]), "v"(w[11]),
        "v"(w[12]), "v"(w[13]), "v"(w[14]), "v"(w[15]));
}

#define STEP16(C0, C1, C2, C3)              \
  do {                                      \
    step_r(h, (C0).x, w, wih, bias);        \
    step_r(h, (C0).y, w, wih, bias);        \
    step_r(h, (C0).z, w, wih, bias);        \
    step_r(h, (C0).w, w, wih, bias);        \
    step_r(h, (C1).x, w, wih, bias);        \
    step_r(h, (C1).y, w, wih, bias);        \
    step_r(h, (C1).z, w, wih, bias);        \
    step_r(h, (C1).w, w, wih, bias);        \
    step_r(h, (C2).x, w, wih, bias);        \
    step_r(h, (C2).y, w, wih, bias);        \
    step_r(h, (C2).z, w, wih, bias);        \
    step_r(h, (C2).w, w, wih, bias);        \
    step_r(h, (C3).x, w, wih, bias);        \
    step_r(h, (C3).y, w, wih, bias);        \
    step_r(h, (C3).z, w, wih, bias);        \
    step_r(h, (C3).w, w, wih, bias);        \
  } while (0)

// --- kernel -----------------------------------------------------------------
__global__ __launch_bounds__(256) void rnn_relu_kernel(
    const float* __restrict__ x, const float* __restrict__ W_ih,
    const float* __restrict__ b_ih, const float* __restrict__ W_hh,
    const float* __restrict__ b_hh, const float* __restrict__ W_fc,
    const float* __restrict__ b_fc, float* __restrict__ out) {
  const int tid = threadIdx.x;
  const int j   = tid & 15;                        // h index owned by this lane
  const int b   = blockIdx.x * 16 + (tid >> 4);    // batch per 16-lane row

  // Probe row_ror:1 direction (ctrl 0x121 == asm row_ror:1), R1/R2-proven.
  int pr = __builtin_amdgcn_update_dpp(0, j, 0x121, 0xF, 0xF, true);
  const bool plus = (pr == ((j + 1) & 15));

  // w[s] = W_hh[j][sigma_s(j)] so ror_s(h)*w[s] contributes W_hh[j,k]*h[k].
  float w[16];
#pragma unroll
  for (int s = 0; s < 16; ++s) {
    int k = (j + (plus ? s : (16 - s))) & 15;
    w[s] = W_hh[j * 16 + k];
  }
  const float wih  = W_ih[j];
  const float bias = b_ih[j] + b_hh[j];

  // R6-proven load pipeline: A/B double-buffered f4 quads, loads issued a
  // full 16 steps (~1000+ cyc) before first use; no copies, no branch in body.
  const f4* __restrict__ xr = (const f4*)(x + (size_t)b * T_LEN);

  float h = 0.0f;
  f4 A0 = xr[0], A1 = xr[1], A2 = xr[2], A3 = xr[3];
  f4 B0, B1, B2, B3;
  const f4* p = xr + 4;                    // chunk t0+16 (B buffer source)

#pragma unroll 1
  for (int t0 = 0; t0 < T_LEN; t0 += 32) {
    B0 = p[0]; B1 = p[1]; B2 = p[2]; B3 = p[3];     // load chunk t0+16
    STEP16(A0, A1, A2, A3);                          // steps t0 .. t0+15
    const f4* pa = (t0 + 32 < T_LEN) ? (p + 4) : xr; // wrap on final iter
    A0 = pa[0]; A1 = pa[1]; A2 = pa[2]; A3 = pa[3];  // load chunk t0+32
    STEP16(B0, B1, B2, B3);                          // steps t0+16 .. t0+31
    p += 8;
  }

  // Epilogue: out[b, c] = sum_j h[j] * W_fc[c, j] + b_fc[c]  (R2-proven)
  float p0 = h * W_fc[j];
  float p1 = h * W_fc[16 + j];
  p0 += __int_as_float(__builtin_amdgcn_ds_swizzle(__float_as_int(p0), 0x041F));
  p1 += __int_as_float(__builtin_amdgcn_ds_swizzle(__float_as_int(p1), 0x041F));
  p0 += __int_as_float(__builtin_amdgcn_ds_swizzle(__float_as_int(p0), 0x081F));
  p1 += __int_as_float(__builtin_amdgcn_ds_swizzle(__float_as_int(p1), 0x081F));
  p0 += __int_as_float(__builtin_amdgcn_ds_swizzle(__float_as_int(p0), 0x101F));
  p1 += __int_as_float(__builtin_amdgcn_ds_swizzle(__float_as_int(p1), 0x101F));
  p0 += __int_as_float(__builtin_amdgcn_ds_swizzle(__float_as_int(p0), 0x201F));
  p1 += __int_as_float(__builtin_amdgcn_ds_swizzle(__float_as_int(p1), 0x201F));

  if (j == 0) {
    out[b * 2 + 0] = p0 + b_fc[0];
    out[b * 2 + 1] = p1 + b_fc[1];
  }
}

// --- launch -----------------------------------------------------------------
extern "C" void kernel_launch(void* const* d_in, const int* in_sizes, int n_in,
                              void* d_out, int out_size, void* d_ws, size_t ws_size,
                              hipStream_t stream) {
  const float* x    = (const float*)d_in[0];
  const float* W_ih = (const float*)d_in[1];
  const float* b_ih = (const float*)d_in[2];
  const float* W_hh = (const float*)d_in[3];
  const float* b_hh = (const float*)d_in[4];
  const float* W_fc = (const float*)d_in[5];
  const float* b_fc = (const float*)d_in[6];
  float* out = (float*)d_out;

  const int B = 4096;
  dim3 grid(B / 16);   // 256 blocks: 4 batches per wave, 1024 waves = 1/SIMD
  dim3 block(256);
  hipLaunchKernelGGL(rnn_relu_kernel, grid, block, 0, stream,
                     x, W_ih, b_ih, W_hh, b_hh, W_fc, b_fc, out);
}